// Round 8
// baseline (575.554 us; speedup 1.0000x reference)
//
#include <hip/hip_runtime.h>
#include <hip/hip_bf16.h>
#include <math.h>

#define NN 16384
#define BB 64
#define NPG 256
#define KNN 100
#define FIN 5
#define HH 128
#define H2 768
#define SLOPE 0.01f

// Inputs are fp32 (verified R3: detect flag=0, absmax 0.0). Dtype-agnostic machinery kept:
// bn_gamma all-ones -> first 32 bits 0x3F800000 (fp32) vs 0x3F803F80 (bf16).
__device__ __forceinline__ float loadin(const void* p, size_t i, int bf) {
    return bf ? __bfloat162float(((const __hip_bfloat16*)p)[i]) : ((const float*)p)[i];
}
template <typename T>
__device__ __forceinline__ float ldT(const T* p, size_t i) { return (float)p[i]; }
template <>
__device__ __forceinline__ float ldT<__hip_bfloat16>(const __hip_bfloat16* p, size_t i) {
    return __bfloat162float(p[i]);
}
__device__ __forceinline__ float4 ldT4(const float* p) { return *(const float4*)p; }
__device__ __forceinline__ float4 ldT4(const __hip_bfloat16* p) {
    ushort4 u = *(const ushort4*)p;
    return make_float4(__uint_as_float((unsigned)u.x << 16),
                       __uint_as_float((unsigned)u.y << 16),
                       __uint_as_float((unsigned)u.z << 16),
                       __uint_as_float((unsigned)u.w << 16));
}
__device__ __forceinline__ void stage_chunk(float* dst, const float* src, int n, int t) {
    const float4* s = (const float4*)src;
    float4* d = (float4*)dst;
    int n4 = n >> 2;
    for (int i = t; i < n4; i += 256) d[i] = s[i];
}
__device__ __forceinline__ void stage_chunk(float* dst, const __hip_bfloat16* src, int n, int t) {
    const ushort4* s = (const ushort4*)src;
    int n4 = n >> 2;
    for (int i = t; i < n4; i += 256) {
        ushort4 u = s[i];
        dst[i * 4 + 0] = __uint_as_float((unsigned)u.x << 16);
        dst[i * 4 + 1] = __uint_as_float((unsigned)u.y << 16);
        dst[i * 4 + 2] = __uint_as_float((unsigned)u.z << 16);
        dst[i * 4 + 3] = __uint_as_float((unsigned)u.w << 16);
    }
}

__global__ void detect_kernel(const void* gamma, int* flag) {
    *flag = (((const unsigned int*)gamma)[0] == 0x3F803F80u) ? 1 : 0;
}

__global__ void cvt_kernel(const void* in, const int* flagp, float* __restrict__ out, int n) {
    int i = blockIdx.x * 256 + threadIdx.x;
    int bf = *flagp;
    if (i < n) out[i] = loadin(in, i, bf);
}

// ---------------- KNN v3: wave-per-row ballot rank count ----------------
// key_j = (bits(d2_j) << 32) | j; rank = #{key < key_j} == stable top-k (lower index
// wins ties), matching jax.lax.top_k. Each wave owns one row; lane holds 4 keys in
// VGPRs. Per candidate j: 1 v_readlane (hi bits; lo bits == j, the loop counter) +
// 4 v_cmp_lt_u64 ballots covering all 256 compares + scalar popcounts (co-issued) +
// 2 cmp/cndmask to place j into the rank-slot register (cnt is wave-uniform).
// One coalesced byte-store per wave at the end. Block = 4 waves = 4 rows, shared xg.
__global__ __launch_bounds__(256) void knn_kernel(const float* __restrict__ xf,
                                                  unsigned char* __restrict__ nbr) {
    int blk = blockIdx.x;
    int b = blk >> 6;                       // graph (64 blocks per graph)
    int wave = threadIdx.x >> 6;
    int lane = threadIdx.x & 63;
    int il = ((blk & 63) << 2) + wave;      // local row
    __shared__ float xg[NPG * FIN];
    for (int idx = threadIdx.x; idx < NPG * FIN; idx += 256)
        xg[idx] = xf[(size_t)b * NPG * FIN + idx];
    __syncthreads();
    float xi0 = xg[il*FIN+0], xi1 = xg[il*FIN+1], xi2 = xg[il*FIN+2],
          xi3 = xg[il*FIN+3], xi4 = xg[il*FIN+4];
    unsigned khi[4];
    unsigned long long kk[4];
    #pragma unroll
    for (int q = 0; q < 4; ++q) {
        int j = q * 64 + lane;
        float d0 = xi0 - xg[j*FIN+0];
        float d1 = xi1 - xg[j*FIN+1];
        float d2_ = xi2 - xg[j*FIN+2];
        float d3 = xi3 - xg[j*FIN+3];
        float d4 = xi4 - xg[j*FIN+4];
        float dd = d0*d0;
        dd += d1*d1; dd += d2_*d2_; dd += d3*d3; dd += d4*d4;
        if (j == il) dd = 1e30f;            // exclude self
        khi[q] = __float_as_uint(dd);
        kk[q] = ((unsigned long long)khi[q] << 32) | (unsigned)j;
    }
    unsigned out0 = 0, out1 = 0;
    #define KNN_RANK64(Q)                                                          \
    _Pragma("unroll 8")                                                            \
    for (int jj = 0; jj < 64; ++jj) {                                              \
        unsigned shi = (unsigned)__builtin_amdgcn_readlane((int)khi[Q], jj);       \
        unsigned long long kj = ((unsigned long long)shi << 32)                    \
                              | (unsigned)(Q * 64 + jj);                           \
        int cnt = __popcll(__ballot(kk[0] < kj)) + __popcll(__ballot(kk[1] < kj))  \
                + __popcll(__ballot(kk[2] < kj)) + __popcll(__ballot(kk[3] < kj)); \
        cnt = __builtin_amdgcn_readfirstlane(cnt);                                 \
        out0 = (lane == cnt)      ? (unsigned)(Q * 64 + jj) : out0;                \
        out1 = (lane == cnt - 64) ? (unsigned)(Q * 64 + jj) : out1;                \
    }
    KNN_RANK64(0) KNN_RANK64(1) KNN_RANK64(2) KNN_RANK64(3)
    #undef KNN_RANK64
    size_t rowbase = (size_t)(b * NPG + il) * KNN;
    nbr[rowbase + lane] = (unsigned char)out0;               // ranks 0..63
    if (lane < KNN - 64)
        nbr[rowbase + 64 + lane] = (unsigned char)out1;      // ranks 64..99
}

// ---------------- aggregation, C=5 ----------------
__global__ void agg5_kernel(const float* __restrict__ hin, const unsigned char* __restrict__ nbr,
                            float* __restrict__ hout, float nrm) {
    int b = blockIdx.x, i = threadIdx.x;
    __shared__ float hs[NPG * FIN];
    for (int idx = threadIdx.x; idx < NPG * FIN; idx += 256)
        hs[idx] = hin[(size_t)b * NPG * FIN + idx];
    __syncthreads();
    const unsigned char* nb = nbr + (size_t)(b * NPG + i) * KNN;
    float a0=0.f, a1=0.f, a2=0.f, a3=0.f, a4=0.f;
    for (int k = 0; k < KNN; ++k) {
        int base = (int)nb[k] * FIN;
        a0 += hs[base+0]; a1 += hs[base+1]; a2 += hs[base+2];
        a3 += hs[base+3]; a4 += hs[base+4];
    }
    size_t o = (size_t)(b * NPG + i) * FIN;
    hout[o+0] = nrm*a0; hout[o+1] = nrm*a1; hout[o+2] = nrm*a2;
    hout[o+3] = nrm*a3; hout[o+4] = nrm*a4;
}

// ---------------- aggregation v2, C=128: grid (B, 4 col-chunks, 4 node-groups) --------------
// LDS tile 256 nodes x 32 cols, stride 36 (16B-aligned rows). 8 threads per node x 4 cols
// -> one aligned ds_read_b128 per neighbor; the 8 octs of a node cover all 32 banks
// exactly once -> conflict-free for any neighbor pattern.
__global__ void agg128_kernel(const float* __restrict__ hin, const unsigned char* __restrict__ nbr,
                              float* __restrict__ hout, float nrm) {
    int b = blockIdx.x;
    int c0 = blockIdx.y * 32;
    int i0 = blockIdx.z * 64;
    __shared__ float hs[NPG * 36];
    int t = threadIdx.x;
    for (int i = t; i < NPG * 8; i += 256) {
        int node = i >> 3, grp = i & 7;
        float4 v = *(const float4*)&hin[((size_t)(b * NPG + node)) * HH + c0 + grp * 4];
        *(float4*)&hs[node * 36 + grp * 4] = v;
    }
    __syncthreads();
    int oct = t & 7;
    #pragma unroll
    for (int pass = 0; pass < 2; ++pass) {
        int il = i0 + pass * 32 + (t >> 3);
        const unsigned char* nb = nbr + (size_t)(b * NPG + il) * KNN;
        float a0 = 0.f, a1 = 0.f, a2 = 0.f, a3 = 0.f;
        #pragma unroll 5
        for (int k4 = 0; k4 < KNN / 4; ++k4) {
            uchar4 n4 = *(const uchar4*)&nb[k4 * 4];
            const float4 v0 = *(const float4*)&hs[(int)n4.x * 36 + oct * 4];
            const float4 v1 = *(const float4*)&hs[(int)n4.y * 36 + oct * 4];
            const float4 v2 = *(const float4*)&hs[(int)n4.z * 36 + oct * 4];
            const float4 v3 = *(const float4*)&hs[(int)n4.w * 36 + oct * 4];
            a0 += v0.x + v1.x + v2.x + v3.x;
            a1 += v0.y + v1.y + v2.y + v3.y;
            a2 += v0.z + v1.z + v2.z + v3.z;
            a3 += v0.w + v1.w + v2.w + v3.w;
        }
        float4 o = make_float4(nrm * a0, nrm * a1, nrm * a2, nrm * a3);
        *(float4*)&hout[((size_t)(b * NPG + il)) * HH + c0 + oct * 4] = o;
    }
}

// ---------------- fused TAGConv matmul: O = leaky(X0@W0 + X1@W1 + X2@W2 + b) ---------------
template <typename T, int KIN>
__device__ __forceinline__ void tagmm_body(
        const float* __restrict__ X0, const float* __restrict__ X1,
        const float* __restrict__ X2,
        const T* __restrict__ W, const T* __restrict__ bias,
        float* __restrict__ O, float* Ws, float* Xs) {
    constexpr int KK = (KIN < 64) ? KIN : 64;
    constexpr int XST = KK + 4;
    int t = threadIdx.x;
    int r0 = blockIdx.x * 16;
    int r = t & 15, cg = t >> 4;
    float acc[8] = {0.f,0.f,0.f,0.f,0.f,0.f,0.f,0.f};
    const float* Xh[3] = {X0, X1, X2};
    for (int h = 0; h < 3; ++h) {
        const float* X = Xh[h];
        for (int k0 = 0; k0 < KIN; k0 += KK) {
            stage_chunk(Ws, W + ((size_t)h * KIN + k0) * HH, KK * HH, t);
            for (int idx = t; idx < 16 * KK; idx += 256) {
                int rr = idx / KK, k = idx - rr * KK;
                Xs[rr * XST + k] = X[(size_t)(r0 + rr) * KIN + k0 + k];
            }
            __syncthreads();
            #pragma unroll 8
            for (int k = 0; k < KK; ++k) {
                float xv = Xs[r * XST + k];
                const float4 wa = *(const float4*)&Ws[k * HH + cg * 8];
                const float4 wb = *(const float4*)&Ws[k * HH + cg * 8 + 4];
                acc[0] += xv * wa.x; acc[1] += xv * wa.y;
                acc[2] += xv * wa.z; acc[3] += xv * wa.w;
                acc[4] += xv * wb.x; acc[5] += xv * wb.y;
                acc[6] += xv * wb.z; acc[7] += xv * wb.w;
            }
            __syncthreads();
        }
    }
    size_t orow = (size_t)(r0 + r) * HH + cg * 8;
    #pragma unroll
    for (int m = 0; m < 8; ++m) {
        float v = acc[m] + ldT(bias, cg * 8 + m);
        O[orow + m] = v > 0.f ? v : SLOPE * v;
    }
}

__global__ __launch_bounds__(256) void tagmm5_kernel(
        const float* X0, const float* X1, const float* X2,
        const void* W, const void* bias, float* O, const int* flagp) {
    __shared__ float Ws[5 * HH];
    __shared__ float Xs[16 * 9];
    if (*flagp) tagmm_body<__hip_bfloat16, FIN>(X0, X1, X2, (const __hip_bfloat16*)W,
                                                (const __hip_bfloat16*)bias, O, Ws, Xs);
    else        tagmm_body<float, FIN>(X0, X1, X2, (const float*)W,
                                       (const float*)bias, O, Ws, Xs);
}

__global__ __launch_bounds__(256) void tagmm128_kernel(
        const float* X0, const float* X1, const float* X2,
        const void* W, const void* bias, float* O, const int* flagp) {
    __shared__ float Ws[64 * HH];     // 32 KB
    __shared__ float Xs[16 * 68];     // 4.3 KB
    if (*flagp) tagmm_body<__hip_bfloat16, HH>(X0, X1, X2, (const __hip_bfloat16*)W,
                                               (const __hip_bfloat16*)bias, O, Ws, Xs);
    else        tagmm_body<float, HH>(X0, X1, X2, (const float*)W,
                                      (const float*)bias, O, Ws, Xs);
}

// ---------------- pooling: mean+max over 256 nodes per graph ----------------
__global__ void pool_kernel(const float* __restrict__ h, float* __restrict__ g, int gc0) {
    int b = blockIdx.x, c = threadIdx.x;   // 128 threads
    const float* hp = h + (size_t)b * NPG * HH + c;
    float s = 0.f, mx = -INFINITY;
    for (int i = 0; i < NPG; ++i) {
        float v = hp[(size_t)i * HH];
        s += v; mx = fmaxf(mx, v);
    }
    g[(size_t)b * H2 + gc0 + c] = s * (1.0f / NPG);
    g[(size_t)b * H2 + gc0 + HH + c] = mx;
}

// ---------------- batchnorm over batch dim (64), in place on g[64,768] ----------------
__global__ void bn_kernel(float* __restrict__ g, const void* gamma, const void* beta,
                          const int* flagp) {
    int c = blockIdx.x * 128 + threadIdx.x;
    int bf = *flagp;
    float mu = 0.f;
    for (int b = 0; b < BB; ++b) mu += g[(size_t)b * H2 + c];
    mu *= (1.0f / BB);
    float var = 0.f;
    for (int b = 0; b < BB; ++b) {
        float d = g[(size_t)b * H2 + c] - mu;
        var += d * d;
    }
    var *= (1.0f / BB);
    float rs = 1.0f / sqrtf(var + 1e-5f);
    float ga = loadin(gamma, c, bf), be = loadin(beta, c, bf);
    for (int b = 0; b < BB; ++b)
        g[(size_t)b * H2 + c] = (g[(size_t)b * H2 + c] - mu) * rs * ga + be;
}

// ---------------- MLP layer GEMM: O[64,768] = leaky(X@W + b), block = 64 rows x 16 cols -----
template <typename T>
__device__ __forceinline__ void mlp_layer_body(
        const float* __restrict__ X, const T* __restrict__ W, const T* __restrict__ bias,
        float* __restrict__ O, float* Xs, float* Ws) {
    int t = threadIdx.x;
    int col0 = blockIdx.x * 16;
    int r = t & 63, cg = t >> 6;
    float acc[4] = {0.f, 0.f, 0.f, 0.f};
    for (int k0 = 0; k0 < H2; k0 += 64) {
        const float4* Xg = (const float4*)X;
        for (int i = t; i < 1024; i += 256) {
            int row = i >> 4, q = i & 15;
            float4 v = Xg[(size_t)row * (H2 / 4) + (k0 >> 2) + q];
            float* d = &Xs[row * 65 + q * 4];
            d[0] = v.x; d[1] = v.y; d[2] = v.z; d[3] = v.w;
        }
        {
            int kr = t >> 2, c4 = t & 3;
            float4 v = ldT4(W + (size_t)(k0 + kr) * H2 + col0 + c4 * 4);
            float* d = &Ws[kr * 16 + c4 * 4];
            d[0] = v.x; d[1] = v.y; d[2] = v.z; d[3] = v.w;
        }
        __syncthreads();
        #pragma unroll 8
        for (int k = 0; k < 64; ++k) {
            float xv = Xs[r * 65 + k];
            const float4 wv = *(const float4*)&Ws[k * 16 + cg * 4];
            acc[0] += xv * wv.x; acc[1] += xv * wv.y;
            acc[2] += xv * wv.z; acc[3] += xv * wv.w;
        }
        __syncthreads();
    }
    size_t o = (size_t)r * H2 + col0 + cg * 4;
    #pragma unroll
    for (int m = 0; m < 4; ++m) {
        float v = acc[m] + ldT(bias, col0 + cg * 4 + m);
        O[o + m] = v > 0.f ? v : SLOPE * v;
    }
}

__global__ __launch_bounds__(256) void mlp_layer_kernel(
        const float* X, const void* W, size_t woff, const void* bias, size_t boff,
        float* O, const int* flagp) {
    __shared__ float Xs[64 * 65];   // 16.6 KB
    __shared__ float Ws[64 * 16];   // 4 KB
    if (*flagp) mlp_layer_body<__hip_bfloat16>(X, (const __hip_bfloat16*)W + woff,
                                               (const __hip_bfloat16*)bias + boff, O, Xs, Ws);
    else        mlp_layer_body<float>(X, (const float*)W + woff,
                                      (const float*)bias + boff, O, Xs, Ws);
}

// ---------------- final dot: out[b] = X[b,:] . w + ob ----------------
__global__ void final_kernel(const float* __restrict__ X, const void* w, const void* ob,
                             void* out, const int* flagp) {
    int b = blockIdx.x, t = threadIdx.x;
    int bf = *flagp;
    float p = 0.f;
    for (int j = t; j < H2; j += 256)
        p += X[(size_t)b * H2 + j] * loadin(w, j, bf);
    __shared__ float red[256];
    red[t] = p;
    __syncthreads();
    for (int s = 128; s > 0; s >>= 1) {
        if (t < s) red[t] += red[t + s];
        __syncthreads();
    }
    if (t == 0) {
        float v = red[0] + loadin(ob, 0, bf);
        if (bf) ((__hip_bfloat16*)out)[b] = __float2bfloat16(v);
        else    ((float*)out)[b] = v;
    }
}

extern "C" void kernel_launch(void* const* d_in, const int* in_sizes, int n_in,
                              void* d_out, int out_size, void* d_ws, size_t ws_size,
                              hipStream_t stream) {
    const void* x_in = d_in[0];
    const void* c1w = d_in[2];  const void* c1b = d_in[3];
    const void* c2w = d_in[4];  const void* c2b = d_in[5];
    const void* c3w = d_in[6];  const void* c3b = d_in[7];
    const void* gam = d_in[8];  const void* bet = d_in[9];
    const void* lw  = d_in[10]; const void* lb  = d_in[11];
    const void* ow  = d_in[12]; const void* obb = d_in[13];

    char* w = (char*)d_ws;
    int* flagp = (int*)w;                    w += 16;
    float* xf = (float*)w;                   w += (size_t)NN * FIN * 4;
    unsigned char* nbr = (unsigned char*)w;  w += (size_t)NN * KNN;
    float* t5a = (float*)w;                  w += (size_t)NN * FIN * 4;
    float* t5b = (float*)w;                  w += (size_t)NN * FIN * 4;
    float* bufA = (float*)w;                 w += (size_t)NN * HH * 4;
    float* bufB = (float*)w;                 w += (size_t)NN * HH * 4;
    float* bufC = (float*)w;                 w += (size_t)NN * HH * 4;
    float* bufD = (float*)w;                 w += (size_t)NN * HH * 4;
    float* g = (float*)w;                    w += (size_t)BB * H2 * 4;
    float* mA = (float*)w;                   w += (size_t)BB * H2 * 4;
    float* mB = (float*)w;                   w += (size_t)BB * H2 * 4;

    float dinv = 1.0f / sqrtf((float)KNN);
    float nrm = dinv * dinv;

    detect_kernel<<<1, 1, 0, stream>>>(gam, flagp);
    cvt_kernel<<<(NN * FIN + 255) / 256, 256, 0, stream>>>(x_in, flagp, xf, NN * FIN);
    knn_kernel<<<NN / 4, 256, 0, stream>>>(xf, nbr);

    dim3 conv_grid(NN / 16);
    dim3 agg_grid(BB, 4, 4);

    // ---- conv1 (Cin=5): hops then one fused matmul ----
    agg5_kernel<<<BB, 256, 0, stream>>>(xf, nbr, t5a, nrm);
    agg5_kernel<<<BB, 256, 0, stream>>>(t5a, nbr, t5b, nrm);
    tagmm5_kernel<<<conv_grid, 256, 0, stream>>>(xf, t5a, t5b, c1w, c1b, bufA, flagp);
    pool_kernel<<<BB, 128, 0, stream>>>(bufA, g, 0);

    // ---- conv2: bufA -> bufD ----
    agg128_kernel<<<agg_grid, 256, 0, stream>>>(bufA, nbr, bufB, nrm);
    agg128_kernel<<<agg_grid, 256, 0, stream>>>(bufB, nbr, bufC, nrm);
    tagmm128_kernel<<<conv_grid, 256, 0, stream>>>(bufA, bufB, bufC, c2w, c2b, bufD, flagp);
    pool_kernel<<<BB, 128, 0, stream>>>(bufD, g, 256);

    // ---- conv3: bufD -> bufC ----
    agg128_kernel<<<agg_grid, 256, 0, stream>>>(bufD, nbr, bufA, nrm);
    agg128_kernel<<<agg_grid, 256, 0, stream>>>(bufA, nbr, bufB, nrm);
    tagmm128_kernel<<<conv_grid, 256, 0, stream>>>(bufD, bufA, bufB, c3w, c3b, bufC, flagp);
    pool_kernel<<<BB, 128, 0, stream>>>(bufC, g, 512);

    // ---- batchnorm ----
    bn_kernel<<<6, 128, 0, stream>>>(g, gam, bet, flagp);

    // ---- MLP: 5 GEMM layers, then final dot ----
    float* src = g;
    for (int i = 0; i < 5; ++i) {
        float* dst = (i % 2 == 0) ? mA : mB;
        mlp_layer_kernel<<<H2 / 16, 256, 0, stream>>>(src, lw, (size_t)i * H2 * H2,
                                                      lb, (size_t)i * H2, dst, flagp);
        src = dst;
    }
    final_kernel<<<BB, 256, 0, stream>>>(src, ow, obb, d_out, flagp);
}

// Round 9
// 530.049 us; speedup vs baseline: 1.0859x; 1.0859x over previous
//
#include <hip/hip_runtime.h>
#include <hip/hip_bf16.h>
#include <math.h>

#define NN 16384
#define BB 64
#define NPG 256
#define KNN 100
#define FIN 5
#define HH 128
#define H2 768
#define SLOPE 0.01f

// Inputs are fp32 (verified R3: detect flag=0, absmax 0.0). Dtype-agnostic machinery kept:
// bn_gamma all-ones -> first 32 bits 0x3F800000 (fp32) vs 0x3F803F80 (bf16).
__device__ __forceinline__ float loadin(const void* p, size_t i, int bf) {
    return bf ? __bfloat162float(((const __hip_bfloat16*)p)[i]) : ((const float*)p)[i];
}
template <typename T>
__device__ __forceinline__ float ldT(const T* p, size_t i) { return (float)p[i]; }
template <>
__device__ __forceinline__ float ldT<__hip_bfloat16>(const __hip_bfloat16* p, size_t i) {
    return __bfloat162float(p[i]);
}
__device__ __forceinline__ float4 ldT4(const float* p) { return *(const float4*)p; }
__device__ __forceinline__ float4 ldT4(const __hip_bfloat16* p) {
    ushort4 u = *(const ushort4*)p;
    return make_float4(__uint_as_float((unsigned)u.x << 16),
                       __uint_as_float((unsigned)u.y << 16),
                       __uint_as_float((unsigned)u.z << 16),
                       __uint_as_float((unsigned)u.w << 16));
}
__device__ __forceinline__ void stage_chunk(float* dst, const float* src, int n, int t) {
    const float4* s = (const float4*)src;
    float4* d = (float4*)dst;
    int n4 = n >> 2;
    for (int i = t; i < n4; i += 256) d[i] = s[i];
}
__device__ __forceinline__ void stage_chunk(float* dst, const __hip_bfloat16* src, int n, int t) {
    const ushort4* s = (const ushort4*)src;
    int n4 = n >> 2;
    for (int i = t; i < n4; i += 256) {
        ushort4 u = s[i];
        dst[i * 4 + 0] = __uint_as_float((unsigned)u.x << 16);
        dst[i * 4 + 1] = __uint_as_float((unsigned)u.y << 16);
        dst[i * 4 + 2] = __uint_as_float((unsigned)u.z << 16);
        dst[i * 4 + 3] = __uint_as_float((unsigned)u.w << 16);
    }
}

__global__ void detect_kernel(const void* gamma, int* flag) {
    *flag = (((const unsigned int*)gamma)[0] == 0x3F803F80u) ? 1 : 0;
}

__global__ void cvt_kernel(const void* in, const int* flagp, float* __restrict__ out, int n) {
    int i = blockIdx.x * 256 + threadIdx.x;
    int bf = *flagp;
    if (i < n) out[i] = loadin(in, i, bf);
}

// ---------------- KNN v2 (REVERTED from ballot v3 — measured 79 us vs 107): ----------------
// u64-key rank count. key_j = (bits(d2_j) << 32) | j; rank = #{key < mykey} == stable
// top-k (lower index wins ties), matching jax.lax.top_k. One block per row; thread =
// candidate j computing its own rank; keys read 2-at-a-time via broadcast ds_read_b128.
__global__ void knn_kernel(const float* __restrict__ xf, unsigned char* __restrict__ nbr) {
    int row = blockIdx.x;
    int b = row >> 8, il = row & 255;
    int j = threadIdx.x;
    __shared__ float xg[NPG * FIN];
    __shared__ __align__(16) unsigned long long keys[NPG];
    for (int idx = threadIdx.x; idx < NPG * FIN; idx += 256)
        xg[idx] = xf[(size_t)b * NPG * FIN + idx];
    __syncthreads();
    float xi0 = xg[il*FIN+0], xi1 = xg[il*FIN+1], xi2 = xg[il*FIN+2],
          xi3 = xg[il*FIN+3], xi4 = xg[il*FIN+4];
    float d0 = xi0 - xg[j*FIN+0];
    float d1 = xi1 - xg[j*FIN+1];
    float d2_ = xi2 - xg[j*FIN+2];
    float d3 = xi3 - xg[j*FIN+3];
    float d4 = xi4 - xg[j*FIN+4];
    float dd = d0*d0;
    dd += d1*d1; dd += d2_*d2_; dd += d3*d3; dd += d4*d4;
    if (j == il) dd = 1e30f;
    unsigned long long mykey = ((unsigned long long)__float_as_uint(dd) << 32)
                             | (unsigned long long)j;
    keys[j] = mykey;
    __syncthreads();
    const ulonglong2* kp = (const ulonglong2*)keys;
    int cnt = 0;
    #pragma unroll 16
    for (int q = 0; q < NPG / 2; ++q) {
        ulonglong2 kk = kp[q];
        cnt += (kk.x < mykey) ? 1 : 0;
        cnt += (kk.y < mykey) ? 1 : 0;
    }
    if (cnt < KNN) nbr[(size_t)row * KNN + cnt] = (unsigned char)j;
}

// ---------------- aggregation, C=5, BOTH hops fused (t5a = Lx, t5b = L t5a) -------------
__global__ void agg5x2_kernel(const float* __restrict__ hin,
                              const unsigned char* __restrict__ nbr,
                              float* __restrict__ t5a, float* __restrict__ t5b, float nrm) {
    int b = blockIdx.x, i = threadIdx.x;
    __shared__ float xs[NPG * FIN];
    __shared__ float ys[NPG * FIN];
    for (int idx = threadIdx.x; idx < NPG * FIN; idx += 256)
        xs[idx] = hin[(size_t)b * NPG * FIN + idx];
    __syncthreads();
    const unsigned char* nb = nbr + (size_t)(b * NPG + i) * KNN;
    float a0=0.f, a1=0.f, a2=0.f, a3=0.f, a4=0.f;
    for (int k = 0; k < KNN; ++k) {
        int base = (int)nb[k] * FIN;
        a0 += xs[base+0]; a1 += xs[base+1]; a2 += xs[base+2];
        a3 += xs[base+3]; a4 += xs[base+4];
    }
    a0 *= nrm; a1 *= nrm; a2 *= nrm; a3 *= nrm; a4 *= nrm;
    size_t o = (size_t)(b * NPG + i) * FIN;
    t5a[o+0] = a0; t5a[o+1] = a1; t5a[o+2] = a2; t5a[o+3] = a3; t5a[o+4] = a4;
    ys[i*FIN+0] = a0; ys[i*FIN+1] = a1; ys[i*FIN+2] = a2;
    ys[i*FIN+3] = a3; ys[i*FIN+4] = a4;
    __syncthreads();
    a0=0.f; a1=0.f; a2=0.f; a3=0.f; a4=0.f;
    for (int k = 0; k < KNN; ++k) {
        int base = (int)nb[k] * FIN;
        a0 += ys[base+0]; a1 += ys[base+1]; a2 += ys[base+2];
        a3 += ys[base+3]; a4 += ys[base+4];
    }
    t5b[o+0] = nrm*a0; t5b[o+1] = nrm*a1; t5b[o+2] = nrm*a2;
    t5b[o+3] = nrm*a3; t5b[o+4] = nrm*a4;
}

// ---------------- aggregation v2, C=128: grid (B, 4 col-chunks, 4 node-groups) --------------
// LDS tile 256 nodes x 32 cols, stride 36 (16B-aligned rows). 8 threads per node x 4 cols
// -> one aligned ds_read_b128 per neighbor; the 8 octs of a node cover all 32 banks
// exactly once -> conflict-free for any neighbor pattern.
__global__ void agg128_kernel(const float* __restrict__ hin, const unsigned char* __restrict__ nbr,
                              float* __restrict__ hout, float nrm) {
    int b = blockIdx.x;
    int c0 = blockIdx.y * 32;
    int i0 = blockIdx.z * 64;
    __shared__ float hs[NPG * 36];
    int t = threadIdx.x;
    for (int i = t; i < NPG * 8; i += 256) {
        int node = i >> 3, grp = i & 7;
        float4 v = *(const float4*)&hin[((size_t)(b * NPG + node)) * HH + c0 + grp * 4];
        *(float4*)&hs[node * 36 + grp * 4] = v;
    }
    __syncthreads();
    int oct = t & 7;
    #pragma unroll
    for (int pass = 0; pass < 2; ++pass) {
        int il = i0 + pass * 32 + (t >> 3);
        const unsigned char* nb = nbr + (size_t)(b * NPG + il) * KNN;
        float a0 = 0.f, a1 = 0.f, a2 = 0.f, a3 = 0.f;
        #pragma unroll 5
        for (int k4 = 0; k4 < KNN / 4; ++k4) {
            uchar4 n4 = *(const uchar4*)&nb[k4 * 4];
            const float4 v0 = *(const float4*)&hs[(int)n4.x * 36 + oct * 4];
            const float4 v1 = *(const float4*)&hs[(int)n4.y * 36 + oct * 4];
            const float4 v2 = *(const float4*)&hs[(int)n4.z * 36 + oct * 4];
            const float4 v3 = *(const float4*)&hs[(int)n4.w * 36 + oct * 4];
            a0 += v0.x + v1.x + v2.x + v3.x;
            a1 += v0.y + v1.y + v2.y + v3.y;
            a2 += v0.z + v1.z + v2.z + v3.z;
            a3 += v0.w + v1.w + v2.w + v3.w;
        }
        float4 o = make_float4(nrm * a0, nrm * a1, nrm * a2, nrm * a3);
        *(float4*)&hout[((size_t)(b * NPG + il)) * HH + c0 + oct * 4] = o;
    }
}

// ---------------- fused TAGConv matmul: O = leaky(X0@W0 + X1@W1 + X2@W2 + b) ---------------
template <typename T, int KIN>
__device__ __forceinline__ void tagmm_body(
        const float* __restrict__ X0, const float* __restrict__ X1,
        const float* __restrict__ X2,
        const T* __restrict__ W, const T* __restrict__ bias,
        float* __restrict__ O, float* Ws, float* Xs) {
    constexpr int KK = (KIN < 64) ? KIN : 64;
    constexpr int XST = KK + 4;
    int t = threadIdx.x;
    int r0 = blockIdx.x * 16;
    int r = t & 15, cg = t >> 4;
    float acc[8] = {0.f,0.f,0.f,0.f,0.f,0.f,0.f,0.f};
    const float* Xh[3] = {X0, X1, X2};
    for (int h = 0; h < 3; ++h) {
        const float* X = Xh[h];
        for (int k0 = 0; k0 < KIN; k0 += KK) {
            stage_chunk(Ws, W + ((size_t)h * KIN + k0) * HH, KK * HH, t);
            for (int idx = t; idx < 16 * KK; idx += 256) {
                int rr = idx / KK, k = idx - rr * KK;
                Xs[rr * XST + k] = X[(size_t)(r0 + rr) * KIN + k0 + k];
            }
            __syncthreads();
            #pragma unroll 8
            for (int k = 0; k < KK; ++k) {
                float xv = Xs[r * XST + k];
                const float4 wa = *(const float4*)&Ws[k * HH + cg * 8];
                const float4 wb = *(const float4*)&Ws[k * HH + cg * 8 + 4];
                acc[0] += xv * wa.x; acc[1] += xv * wa.y;
                acc[2] += xv * wa.z; acc[3] += xv * wa.w;
                acc[4] += xv * wb.x; acc[5] += xv * wb.y;
                acc[6] += xv * wb.z; acc[7] += xv * wb.w;
            }
            __syncthreads();
        }
    }
    size_t orow = (size_t)(r0 + r) * HH + cg * 8;
    #pragma unroll
    for (int m = 0; m < 8; ++m) {
        float v = acc[m] + ldT(bias, cg * 8 + m);
        O[orow + m] = v > 0.f ? v : SLOPE * v;
    }
}

__global__ __launch_bounds__(256) void tagmm5_kernel(
        const float* X0, const float* X1, const float* X2,
        const void* W, const void* bias, float* O, const int* flagp) {
    __shared__ float Ws[5 * HH];
    __shared__ float Xs[16 * 9];
    if (*flagp) tagmm_body<__hip_bfloat16, FIN>(X0, X1, X2, (const __hip_bfloat16*)W,
                                                (const __hip_bfloat16*)bias, O, Ws, Xs);
    else        tagmm_body<float, FIN>(X0, X1, X2, (const float*)W,
                                       (const float*)bias, O, Ws, Xs);
}

__global__ __launch_bounds__(256) void tagmm128_kernel(
        const float* X0, const float* X1, const float* X2,
        const void* W, const void* bias, float* O, const int* flagp) {
    __shared__ float Ws[64 * HH];     // 32 KB
    __shared__ float Xs[16 * 68];     // 4.3 KB
    if (*flagp) tagmm_body<__hip_bfloat16, HH>(X0, X1, X2, (const __hip_bfloat16*)W,
                                               (const __hip_bfloat16*)bias, O, Ws, Xs);
    else        tagmm_body<float, HH>(X0, X1, X2, (const float*)W,
                                      (const float*)bias, O, Ws, Xs);
}

// ---------------- pooling v2: mean+max over 256 nodes, 1024 threads (8 row-groups) ---------
// Old version: 128 threads x 256 serial strided loads -> latency-bound (2 waves/block,
// 64 blocks). Now 8x the loads in flight + LDS tree combine.
__global__ __launch_bounds__(1024) void pool_kernel(const float* __restrict__ h,
                                                    float* __restrict__ g, int gc0) {
    int b = blockIdx.x;
    int c = threadIdx.x & 127, q = threadIdx.x >> 7;   // col, row-group
    const float* hp = h + (size_t)b * NPG * HH + (size_t)q * 32 * HH + c;
    float s = 0.f, mx = -INFINITY;
    #pragma unroll 8
    for (int i = 0; i < 32; ++i) {
        float v = hp[(size_t)i * HH];
        s += v; mx = fmaxf(mx, v);
    }
    __shared__ float ss[8][128];
    __shared__ float sm[8][128];
    ss[q][c] = s; sm[q][c] = mx;
    __syncthreads();
    if (q == 0) {
        #pragma unroll
        for (int k = 1; k < 8; ++k) {
            s += ss[k][c];
            mx = fmaxf(mx, sm[k][c]);
        }
        g[(size_t)b * H2 + gc0 + c] = s * (1.0f / NPG);
        g[(size_t)b * H2 + gc0 + HH + c] = mx;
    }
}

// ---------------- batchnorm over batch dim (64), in place on g[64,768] ----------------
__global__ void bn_kernel(float* __restrict__ g, const void* gamma, const void* beta,
                          const int* flagp) {
    int c = blockIdx.x * 128 + threadIdx.x;
    int bf = *flagp;
    float mu = 0.f;
    for (int b = 0; b < BB; ++b) mu += g[(size_t)b * H2 + c];
    mu *= (1.0f / BB);
    float var = 0.f;
    for (int b = 0; b < BB; ++b) {
        float d = g[(size_t)b * H2 + c] - mu;
        var += d * d;
    }
    var *= (1.0f / BB);
    float rs = 1.0f / sqrtf(var + 1e-5f);
    float ga = loadin(gamma, c, bf), be = loadin(beta, c, bf);
    for (int b = 0; b < BB; ++b)
        g[(size_t)b * H2 + c] = (g[(size_t)b * H2 + c] - mu) * rs * ga + be;
}

// ---------------- MLP layer GEMM: O[64,768] = leaky(X@W + b), block = 64 rows x 16 cols -----
template <typename T>
__device__ __forceinline__ void mlp_layer_body(
        const float* __restrict__ X, const T* __restrict__ W, const T* __restrict__ bias,
        float* __restrict__ O, float* Xs, float* Ws) {
    int t = threadIdx.x;
    int col0 = blockIdx.x * 16;
    int r = t & 63, cg = t >> 6;
    float acc[4] = {0.f, 0.f, 0.f, 0.f};
    for (int k0 = 0; k0 < H2; k0 += 64) {
        const float4* Xg = (const float4*)X;
        for (int i = t; i < 1024; i += 256) {
            int row = i >> 4, q = i & 15;
            float4 v = Xg[(size_t)row * (H2 / 4) + (k0 >> 2) + q];
            float* d = &Xs[row * 65 + q * 4];
            d[0] = v.x; d[1] = v.y; d[2] = v.z; d[3] = v.w;
        }
        {
            int kr = t >> 2, c4 = t & 3;
            float4 v = ldT4(W + (size_t)(k0 + kr) * H2 + col0 + c4 * 4);
            float* d = &Ws[kr * 16 + c4 * 4];
            d[0] = v.x; d[1] = v.y; d[2] = v.z; d[3] = v.w;
        }
        __syncthreads();
        #pragma unroll 8
        for (int k = 0; k < 64; ++k) {
            float xv = Xs[r * 65 + k];
            const float4 wv = *(const float4*)&Ws[k * 16 + cg * 4];
            acc[0] += xv * wv.x; acc[1] += xv * wv.y;
            acc[2] += xv * wv.z; acc[3] += xv * wv.w;
        }
        __syncthreads();
    }
    size_t o = (size_t)r * H2 + col0 + cg * 4;
    #pragma unroll
    for (int m = 0; m < 4; ++m) {
        float v = acc[m] + ldT(bias, col0 + cg * 4 + m);
        O[o + m] = v > 0.f ? v : SLOPE * v;
    }
}

__global__ __launch_bounds__(256) void mlp_layer_kernel(
        const float* X, const void* W, size_t woff, const void* bias, size_t boff,
        float* O, const int* flagp) {
    __shared__ float Xs[64 * 65];   // 16.6 KB
    __shared__ float Ws[64 * 16];   // 4 KB
    if (*flagp) mlp_layer_body<__hip_bfloat16>(X, (const __hip_bfloat16*)W + woff,
                                               (const __hip_bfloat16*)bias + boff, O, Xs, Ws);
    else        mlp_layer_body<float>(X, (const float*)W + woff,
                                      (const float*)bias + boff, O, Xs, Ws);
}

// ---------------- final dot: out[b] = X[b,:] . w + ob ----------------
__global__ void final_kernel(const float* __restrict__ X, const void* w, const void* ob,
                             void* out, const int* flagp) {
    int b = blockIdx.x, t = threadIdx.x;
    int bf = *flagp;
    float p = 0.f;
    for (int j = t; j < H2; j += 256)
        p += X[(size_t)b * H2 + j] * loadin(w, j, bf);
    __shared__ float red[256];
    red[t] = p;
    __syncthreads();
    for (int s = 128; s > 0; s >>= 1) {
        if (t < s) red[t] += red[t + s];
        __syncthreads();
    }
    if (t == 0) {
        float v = red[0] + loadin(ob, 0, bf);
        if (bf) ((__hip_bfloat16*)out)[b] = __float2bfloat16(v);
        else    ((float*)out)[b] = v;
    }
}

extern "C" void kernel_launch(void* const* d_in, const int* in_sizes, int n_in,
                              void* d_out, int out_size, void* d_ws, size_t ws_size,
                              hipStream_t stream) {
    const void* x_in = d_in[0];
    const void* c1w = d_in[2];  const void* c1b = d_in[3];
    const void* c2w = d_in[4];  const void* c2b = d_in[5];
    const void* c3w = d_in[6];  const void* c3b = d_in[7];
    const void* gam = d_in[8];  const void* bet = d_in[9];
    const void* lw  = d_in[10]; const void* lb  = d_in[11];
    const void* ow  = d_in[12]; const void* obb = d_in[13];

    char* w = (char*)d_ws;
    int* flagp = (int*)w;                    w += 16;
    float* xf = (float*)w;                   w += (size_t)NN * FIN * 4;
    unsigned char* nbr = (unsigned char*)w;  w += (size_t)NN * KNN;
    float* t5a = (float*)w;                  w += (size_t)NN * FIN * 4;
    float* t5b = (float*)w;                  w += (size_t)NN * FIN * 4;
    float* bufA = (float*)w;                 w += (size_t)NN * HH * 4;
    float* bufB = (float*)w;                 w += (size_t)NN * HH * 4;
    float* bufC = (float*)w;                 w += (size_t)NN * HH * 4;
    float* bufD = (float*)w;                 w += (size_t)NN * HH * 4;
    float* g = (float*)w;                    w += (size_t)BB * H2 * 4;
    float* mA = (float*)w;                   w += (size_t)BB * H2 * 4;
    float* mB = (float*)w;                   w += (size_t)BB * H2 * 4;

    float dinv = 1.0f / sqrtf((float)KNN);
    float nrm = dinv * dinv;

    detect_kernel<<<1, 1, 0, stream>>>(gam, flagp);
    cvt_kernel<<<(NN * FIN + 255) / 256, 256, 0, stream>>>(x_in, flagp, xf, NN * FIN);
    knn_kernel<<<NN, 256, 0, stream>>>(xf, nbr);

    dim3 conv_grid(NN / 16);
    dim3 agg_grid(BB, 4, 4);

    // ---- conv1 (Cin=5): both hops in one launch, then one fused matmul ----
    agg5x2_kernel<<<BB, 256, 0, stream>>>(xf, nbr, t5a, t5b, nrm);
    tagmm5_kernel<<<conv_grid, 256, 0, stream>>>(xf, t5a, t5b, c1w, c1b, bufA, flagp);
    pool_kernel<<<BB, 1024, 0, stream>>>(bufA, g, 0);

    // ---- conv2: bufA -> bufD ----
    agg128_kernel<<<agg_grid, 256, 0, stream>>>(bufA, nbr, bufB, nrm);
    agg128_kernel<<<agg_grid, 256, 0, stream>>>(bufB, nbr, bufC, nrm);
    tagmm128_kernel<<<conv_grid, 256, 0, stream>>>(bufA, bufB, bufC, c2w, c2b, bufD, flagp);
    pool_kernel<<<BB, 1024, 0, stream>>>(bufD, g, 256);

    // ---- conv3: bufD -> bufC ----
    agg128_kernel<<<agg_grid, 256, 0, stream>>>(bufD, nbr, bufA, nrm);
    agg128_kernel<<<agg_grid, 256, 0, stream>>>(bufA, nbr, bufB, nrm);
    tagmm128_kernel<<<conv_grid, 256, 0, stream>>>(bufD, bufA, bufB, c3w, c3b, bufC, flagp);
    pool_kernel<<<BB, 1024, 0, stream>>>(bufC, g, 512);

    // ---- batchnorm ----
    bn_kernel<<<6, 128, 0, stream>>>(g, gam, bet, flagp);

    // ---- MLP: 5 GEMM layers, then final dot ----
    float* src = g;
    for (int i = 0; i < 5; ++i) {
        float* dst = (i % 2 == 0) ? mA : mB;
        mlp_layer_kernel<<<H2 / 16, 256, 0, stream>>>(src, lw, (size_t)i * H2 * H2,
                                                      lb, (size_t)i * H2, dst, flagp);
        src = dst;
    }
    final_kernel<<<BB, 256, 0, stream>>>(src, ow, obb, d_out, flagp);
}

// Round 10
// 416.893 us; speedup vs baseline: 1.3806x; 1.2714x over previous
//
#include <hip/hip_runtime.h>
#include <hip/hip_bf16.h>
#include <math.h>

#define NN 16384
#define BB 64
#define NPG 256
#define KNN 100
#define FIN 5
#define HH 128
#define H2 768
#define SLOPE 0.01f

// Inputs are fp32 (verified R3: detect flag=0, absmax 0.0). Dtype-agnostic machinery kept:
// bn_gamma all-ones -> first 32 bits 0x3F800000 (fp32) vs 0x3F803F80 (bf16).
__device__ __forceinline__ float loadin(const void* p, size_t i, int bf) {
    return bf ? __bfloat162float(((const __hip_bfloat16*)p)[i]) : ((const float*)p)[i];
}
template <typename T>
__device__ __forceinline__ float ldT(const T* p, size_t i) { return (float)p[i]; }
template <>
__device__ __forceinline__ float ldT<__hip_bfloat16>(const __hip_bfloat16* p, size_t i) {
    return __bfloat162float(p[i]);
}
__device__ __forceinline__ float4 ldT4(const float* p) { return *(const float4*)p; }
__device__ __forceinline__ float4 ldT4(const __hip_bfloat16* p) {
    ushort4 u = *(const ushort4*)p;
    return make_float4(__uint_as_float((unsigned)u.x << 16),
                       __uint_as_float((unsigned)u.y << 16),
                       __uint_as_float((unsigned)u.z << 16),
                       __uint_as_float((unsigned)u.w << 16));
}
__device__ __forceinline__ void stage_chunk(float* dst, const float* src, int n, int t) {
    const float4* s = (const float4*)src;
    float4* d = (float4*)dst;
    int n4 = n >> 2;
    for (int i = t; i < n4; i += 256) d[i] = s[i];
}
__device__ __forceinline__ void stage_chunk(float* dst, const __hip_bfloat16* src, int n, int t) {
    const ushort4* s = (const ushort4*)src;
    int n4 = n >> 2;
    for (int i = t; i < n4; i += 256) {
        ushort4 u = s[i];
        dst[i * 4 + 0] = __uint_as_float((unsigned)u.x << 16);
        dst[i * 4 + 1] = __uint_as_float((unsigned)u.y << 16);
        dst[i * 4 + 2] = __uint_as_float((unsigned)u.z << 16);
        dst[i * 4 + 3] = __uint_as_float((unsigned)u.w << 16);
    }
}

__global__ void detect_kernel(const void* gamma, int* flag) {
    *flag = (((const unsigned int*)gamma)[0] == 0x3F803F80u) ? 1 : 0;
}

__global__ void cvt_kernel(const void* in, const int* flagp, float* __restrict__ out, int n) {
    int i = blockIdx.x * 256 + threadIdx.x;
    int bf = *flagp;
    if (i < n) out[i] = loadin(in, i, bf);
}

// ---------------- KNN v2 (79 us known-good; ballot v3 measured 107 -> reverted) -------------
// u64-key rank count. key_j = (bits(d2_j) << 32) | j; rank = #{key < mykey} == stable
// top-k (lower index wins ties), matching jax.lax.top_k.
__global__ void knn_kernel(const float* __restrict__ xf, unsigned char* __restrict__ nbr) {
    int row = blockIdx.x;
    int b = row >> 8, il = row & 255;
    int j = threadIdx.x;
    __shared__ float xg[NPG * FIN];
    __shared__ __align__(16) unsigned long long keys[NPG];
    for (int idx = threadIdx.x; idx < NPG * FIN; idx += 256)
        xg[idx] = xf[(size_t)b * NPG * FIN + idx];
    __syncthreads();
    float xi0 = xg[il*FIN+0], xi1 = xg[il*FIN+1], xi2 = xg[il*FIN+2],
          xi3 = xg[il*FIN+3], xi4 = xg[il*FIN+4];
    float d0 = xi0 - xg[j*FIN+0];
    float d1 = xi1 - xg[j*FIN+1];
    float d2_ = xi2 - xg[j*FIN+2];
    float d3 = xi3 - xg[j*FIN+3];
    float d4 = xi4 - xg[j*FIN+4];
    float dd = d0*d0;
    dd += d1*d1; dd += d2_*d2_; dd += d3*d3; dd += d4*d4;
    if (j == il) dd = 1e30f;
    unsigned long long mykey = ((unsigned long long)__float_as_uint(dd) << 32)
                             | (unsigned long long)j;
    keys[j] = mykey;
    __syncthreads();
    const ulonglong2* kp = (const ulonglong2*)keys;
    int cnt = 0;
    #pragma unroll 16
    for (int q = 0; q < NPG / 2; ++q) {
        ulonglong2 kk = kp[q];
        cnt += (kk.x < mykey) ? 1 : 0;
        cnt += (kk.y < mykey) ? 1 : 0;
    }
    if (cnt < KNN) nbr[(size_t)row * KNN + cnt] = (unsigned char)j;
}

// ---------------- aggregation, C=5, BOTH hops fused ----------------
__global__ void agg5x2_kernel(const float* __restrict__ hin,
                              const unsigned char* __restrict__ nbr,
                              float* __restrict__ t5a, float* __restrict__ t5b, float nrm) {
    int b = blockIdx.x, i = threadIdx.x;
    __shared__ float xs[NPG * FIN];
    __shared__ float ys[NPG * FIN];
    for (int idx = threadIdx.x; idx < NPG * FIN; idx += 256)
        xs[idx] = hin[(size_t)b * NPG * FIN + idx];
    __syncthreads();
    const unsigned char* nb = nbr + (size_t)(b * NPG + i) * KNN;
    float a0=0.f, a1=0.f, a2=0.f, a3=0.f, a4=0.f;
    for (int k = 0; k < KNN; ++k) {
        int base = (int)nb[k] * FIN;
        a0 += xs[base+0]; a1 += xs[base+1]; a2 += xs[base+2];
        a3 += xs[base+3]; a4 += xs[base+4];
    }
    a0 *= nrm; a1 *= nrm; a2 *= nrm; a3 *= nrm; a4 *= nrm;
    size_t o = (size_t)(b * NPG + i) * FIN;
    t5a[o+0] = a0; t5a[o+1] = a1; t5a[o+2] = a2; t5a[o+3] = a3; t5a[o+4] = a4;
    ys[i*FIN+0] = a0; ys[i*FIN+1] = a1; ys[i*FIN+2] = a2;
    ys[i*FIN+3] = a3; ys[i*FIN+4] = a4;
    __syncthreads();
    a0=0.f; a1=0.f; a2=0.f; a3=0.f; a4=0.f;
    for (int k = 0; k < KNN; ++k) {
        int base = (int)nb[k] * FIN;
        a0 += ys[base+0]; a1 += ys[base+1]; a2 += ys[base+2];
        a3 += ys[base+3]; a4 += ys[base+4];
    }
    t5b[o+0] = nrm*a0; t5b[o+1] = nrm*a1; t5b[o+2] = nrm*a2;
    t5b[o+3] = nrm*a3; t5b[o+4] = nrm*a4;
}

// ---------------- aggregation, C=128: conflict-free oct gather ----------------
__global__ void agg128_kernel(const float* __restrict__ hin, const unsigned char* __restrict__ nbr,
                              float* __restrict__ hout, float nrm) {
    int b = blockIdx.x;
    int c0 = blockIdx.y * 32;
    int i0 = blockIdx.z * 64;
    __shared__ float hs[NPG * 36];
    int t = threadIdx.x;
    for (int i = t; i < NPG * 8; i += 256) {
        int node = i >> 3, grp = i & 7;
        float4 v = *(const float4*)&hin[((size_t)(b * NPG + node)) * HH + c0 + grp * 4];
        *(float4*)&hs[node * 36 + grp * 4] = v;
    }
    __syncthreads();
    int oct = t & 7;
    #pragma unroll
    for (int pass = 0; pass < 2; ++pass) {
        int il = i0 + pass * 32 + (t >> 3);
        const unsigned char* nb = nbr + (size_t)(b * NPG + il) * KNN;
        float a0 = 0.f, a1 = 0.f, a2 = 0.f, a3 = 0.f;
        #pragma unroll 5
        for (int k4 = 0; k4 < KNN / 4; ++k4) {
            uchar4 n4 = *(const uchar4*)&nb[k4 * 4];
            const float4 v0 = *(const float4*)&hs[(int)n4.x * 36 + oct * 4];
            const float4 v1 = *(const float4*)&hs[(int)n4.y * 36 + oct * 4];
            const float4 v2 = *(const float4*)&hs[(int)n4.z * 36 + oct * 4];
            const float4 v3 = *(const float4*)&hs[(int)n4.w * 36 + oct * 4];
            a0 += v0.x + v1.x + v2.x + v3.x;
            a1 += v0.y + v1.y + v2.y + v3.y;
            a2 += v0.z + v1.z + v2.z + v3.z;
            a3 += v0.w + v1.w + v2.w + v3.w;
        }
        float4 o = make_float4(nrm * a0, nrm * a1, nrm * a2, nrm * a3);
        *(float4*)&hout[((size_t)(b * NPG + il)) * HH + c0 + oct * 4] = o;
    }
}

// ---------------- tagmm5: generic body (K=5 per hop, small) ----------------
template <typename T, int KIN>
__device__ __forceinline__ void tagmm_body(
        const float* __restrict__ X0, const float* __restrict__ X1,
        const float* __restrict__ X2,
        const T* __restrict__ W, const T* __restrict__ bias,
        float* __restrict__ O, float* Ws, float* Xs) {
    constexpr int KK = (KIN < 64) ? KIN : 64;
    constexpr int XST = KK + 4;
    int t = threadIdx.x;
    int r0 = blockIdx.x * 16;
    int r = t & 15, cg = t >> 4;
    float acc[8] = {0.f,0.f,0.f,0.f,0.f,0.f,0.f,0.f};
    const float* Xh[3] = {X0, X1, X2};
    for (int h = 0; h < 3; ++h) {
        const float* X = Xh[h];
        for (int k0 = 0; k0 < KIN; k0 += KK) {
            stage_chunk(Ws, W + ((size_t)h * KIN + k0) * HH, KK * HH, t);
            for (int idx = t; idx < 16 * KK; idx += 256) {
                int rr = idx / KK, k = idx - rr * KK;
                Xs[rr * XST + k] = X[(size_t)(r0 + rr) * KIN + k0 + k];
            }
            __syncthreads();
            #pragma unroll 8
            for (int k = 0; k < KK; ++k) {
                float xv = Xs[r * XST + k];
                const float4 wa = *(const float4*)&Ws[k * HH + cg * 8];
                const float4 wb = *(const float4*)&Ws[k * HH + cg * 8 + 4];
                acc[0] += xv * wa.x; acc[1] += xv * wa.y;
                acc[2] += xv * wa.z; acc[3] += xv * wa.w;
                acc[4] += xv * wb.x; acc[5] += xv * wb.y;
                acc[6] += xv * wb.z; acc[7] += xv * wb.w;
            }
            __syncthreads();
        }
    }
    size_t orow = (size_t)(r0 + r) * HH + cg * 8;
    #pragma unroll
    for (int m = 0; m < 8; ++m) {
        float v = acc[m] + ldT(bias, cg * 8 + m);
        O[orow + m] = v > 0.f ? v : SLOPE * v;
    }
}

__global__ __launch_bounds__(256) void tagmm5_kernel(
        const float* X0, const float* X1, const float* X2,
        const void* W, const void* bias, float* O, const int* flagp) {
    __shared__ float Ws[5 * HH];
    __shared__ float Xs[16 * 9];
    if (*flagp) tagmm_body<__hip_bfloat16, FIN>(X0, X1, X2, (const __hip_bfloat16*)W,
                                                (const __hip_bfloat16*)bias, O, Ws, Xs);
    else        tagmm_body<float, FIN>(X0, X1, X2, (const float*)W,
                                       (const float*)bias, O, Ws, Xs);
}

// ---------------- tagmm128 v2: 32 rows x 128 cols, Xs transposed [k][row] ----------------
// Inner loop per k: 1 ds_read_b64 (2 rows) + 2 ds_read_b128 (8 cols) -> 16 FMA
// (2x the FMA:LDS ratio of v1's 16-row tile). Xs stride 34 (b64-aligned; write pattern
// spreads rows over all 32 banks, half-wave 2-way alias = free). Grid NN/32 = 512,
// LDS 40.7 KB -> 2 blocks/CU, 8 waves/CU.
template <typename T>
__device__ __forceinline__ void tagmm128_body(
        const float* __restrict__ X0, const float* __restrict__ X1,
        const float* __restrict__ X2,
        const T* __restrict__ W, const T* __restrict__ bias,
        float* __restrict__ O, float* Ws, float* Xs) {
    int t = threadIdx.x;
    int r0 = blockIdx.x * 32;
    int rp = t & 15, cg = t >> 4;        // row pair (2 rows), 8-col group
    float acc[16];
    #pragma unroll
    for (int m = 0; m < 16; ++m) acc[m] = 0.f;
    const float* Xh[3] = {X0, X1, X2};
    for (int h = 0; h < 3; ++h) {
        const float* X = Xh[h];
        for (int k0 = 0; k0 < HH; k0 += 64) {
            stage_chunk(Ws, W + ((size_t)h * HH + k0) * HH, 64 * HH, t);
            for (int i = t; i < 32 * 16; i += 256) {      // 32 rows x 16 k-quads
                int row = i & 31, kq = i >> 5;
                float4 v = *(const float4*)&X[(size_t)(r0 + row) * HH + k0 + kq * 4];
                Xs[(kq * 4 + 0) * 34 + row] = v.x;
                Xs[(kq * 4 + 1) * 34 + row] = v.y;
                Xs[(kq * 4 + 2) * 34 + row] = v.z;
                Xs[(kq * 4 + 3) * 34 + row] = v.w;
            }
            __syncthreads();
            #pragma unroll 8
            for (int k = 0; k < 64; ++k) {
                const float2 xv = *(const float2*)&Xs[k * 34 + rp * 2];
                const float4 wa = *(const float4*)&Ws[k * HH + cg * 8];
                const float4 wb = *(const float4*)&Ws[k * HH + cg * 8 + 4];
                acc[0] += xv.x * wa.x; acc[1] += xv.x * wa.y;
                acc[2] += xv.x * wa.z; acc[3] += xv.x * wa.w;
                acc[4] += xv.x * wb.x; acc[5] += xv.x * wb.y;
                acc[6] += xv.x * wb.z; acc[7] += xv.x * wb.w;
                acc[8]  += xv.y * wa.x; acc[9]  += xv.y * wa.y;
                acc[10] += xv.y * wa.z; acc[11] += xv.y * wa.w;
                acc[12] += xv.y * wb.x; acc[13] += xv.y * wb.y;
                acc[14] += xv.y * wb.z; acc[15] += xv.y * wb.w;
            }
            __syncthreads();
        }
    }
    #pragma unroll
    for (int rr = 0; rr < 2; ++rr) {
        size_t orow = (size_t)(r0 + rp * 2 + rr) * HH + cg * 8;
        #pragma unroll
        for (int m = 0; m < 8; ++m) {
            float v = acc[rr * 8 + m] + ldT(bias, cg * 8 + m);
            O[orow + m] = v > 0.f ? v : SLOPE * v;
        }
    }
}

__global__ __launch_bounds__(256) void tagmm128_kernel(
        const float* X0, const float* X1, const float* X2,
        const void* W, const void* bias, float* O, const int* flagp) {
    __shared__ float Ws[64 * HH];     // 32 KB
    __shared__ float Xs[64 * 34];     // 8.7 KB
    if (*flagp) tagmm128_body<__hip_bfloat16>(X0, X1, X2, (const __hip_bfloat16*)W,
                                              (const __hip_bfloat16*)bias, O, Ws, Xs);
    else        tagmm128_body<float>(X0, X1, X2, (const float*)W,
                                     (const float*)bias, O, Ws, Xs);
}

// ---------------- pooling: mean+max over 256 nodes, 1024 threads ----------------
__global__ __launch_bounds__(1024) void pool_kernel(const float* __restrict__ h,
                                                    float* __restrict__ g, int gc0) {
    int b = blockIdx.x;
    int c = threadIdx.x & 127, q = threadIdx.x >> 7;
    const float* hp = h + (size_t)b * NPG * HH + (size_t)q * 32 * HH + c;
    float s = 0.f, mx = -INFINITY;
    #pragma unroll 8
    for (int i = 0; i < 32; ++i) {
        float v = hp[(size_t)i * HH];
        s += v; mx = fmaxf(mx, v);
    }
    __shared__ float ss[8][128];
    __shared__ float sm[8][128];
    ss[q][c] = s; sm[q][c] = mx;
    __syncthreads();
    if (q == 0) {
        #pragma unroll
        for (int k = 1; k < 8; ++k) {
            s += ss[k][c];
            mx = fmaxf(mx, sm[k][c]);
        }
        g[(size_t)b * H2 + gc0 + c] = s * (1.0f / NPG);
        g[(size_t)b * H2 + gc0 + HH + c] = mx;
    }
}

// ---------------- batchnorm over batch dim (64) ----------------
__global__ void bn_kernel(float* __restrict__ g, const void* gamma, const void* beta,
                          const int* flagp) {
    int c = blockIdx.x * 128 + threadIdx.x;
    int bf = *flagp;
    float mu = 0.f;
    for (int b = 0; b < BB; ++b) mu += g[(size_t)b * H2 + c];
    mu *= (1.0f / BB);
    float var = 0.f;
    for (int b = 0; b < BB; ++b) {
        float d = g[(size_t)b * H2 + c] - mu;
        var += d * d;
    }
    var *= (1.0f / BB);
    float rs = 1.0f / sqrtf(var + 1e-5f);
    float ga = loadin(gamma, c, bf), be = loadin(beta, c, bf);
    for (int b = 0; b < BB; ++b)
        g[(size_t)b * H2 + c] = (g[(size_t)b * H2 + c] - mu) * rs * ga + be;
}

// ---------------- MLP layer GEMM v2: double-buffered prefetch ----------------
// 64 rows x 16 cols per block, grid 48. Stage s+1's global loads issued into registers
// before computing stage s; ping-pong LDS buffers, ONE barrier per stage (buffer-reuse
// safety: compute(s-1) on buf[(s+1)&1] completes before the stage s-1 barrier).
template <typename T>
__device__ __forceinline__ void mlp_layer_body(
        const float* __restrict__ X, const T* __restrict__ W, const T* __restrict__ bias,
        float* __restrict__ O, float* Xs0, float* Xs1, float* Ws0, float* Ws1) {
    int t = threadIdx.x;
    int col0 = blockIdx.x * 16;
    int r = t & 63, cg = t >> 6;
    float acc[4] = {0.f, 0.f, 0.f, 0.f};
    const float4* Xg = (const float4*)X;
    float4 xr[4]; float4 wr;
    int kr = t >> 2, c4 = t & 3;
    // prefetch stage 0
    #pragma unroll
    for (int u = 0; u < 4; ++u) {
        int i = t + u * 256;
        xr[u] = Xg[(size_t)(i >> 4) * (H2 / 4) + (i & 15)];
    }
    wr = ldT4(W + (size_t)kr * H2 + col0 + c4 * 4);
    {
        #pragma unroll
        for (int u = 0; u < 4; ++u) {
            int i = t + u * 256;
            float* d = &Xs0[(i >> 4) * 65 + (i & 15) * 4];
            d[0] = xr[u].x; d[1] = xr[u].y; d[2] = xr[u].z; d[3] = xr[u].w;
        }
        float* d = &Ws0[kr * 16 + c4 * 4];
        d[0] = wr.x; d[1] = wr.y; d[2] = wr.z; d[3] = wr.w;
    }
    __syncthreads();
    for (int s = 0; s < 12; ++s) {
        if (s + 1 < 12) {
            int k0 = (s + 1) * 64;
            #pragma unroll
            for (int u = 0; u < 4; ++u) {
                int i = t + u * 256;
                xr[u] = Xg[(size_t)(i >> 4) * (H2 / 4) + (k0 >> 2) + (i & 15)];
            }
            wr = ldT4(W + (size_t)(k0 + kr) * H2 + col0 + c4 * 4);
        }
        const float* Xc = (s & 1) ? Xs1 : Xs0;
        const float* Wc = (s & 1) ? Ws1 : Ws0;
        #pragma unroll 8
        for (int k = 0; k < 64; ++k) {
            float xv = Xc[r * 65 + k];
            const float4 wv = *(const float4*)&Wc[k * 16 + cg * 4];
            acc[0] += xv * wv.x; acc[1] += xv * wv.y;
            acc[2] += xv * wv.z; acc[3] += xv * wv.w;
        }
        if (s + 1 < 12) {
            float* Xn = (s & 1) ? Xs0 : Xs1;
            float* Wn = (s & 1) ? Ws0 : Ws1;
            #pragma unroll
            for (int u = 0; u < 4; ++u) {
                int i = t + u * 256;
                float* d = &Xn[(i >> 4) * 65 + (i & 15) * 4];
                d[0] = xr[u].x; d[1] = xr[u].y; d[2] = xr[u].z; d[3] = xr[u].w;
            }
            float* d = &Wn[kr * 16 + c4 * 4];
            d[0] = wr.x; d[1] = wr.y; d[2] = wr.z; d[3] = wr.w;
            __syncthreads();
        }
    }
    size_t o = (size_t)r * H2 + col0 + cg * 4;
    #pragma unroll
    for (int m = 0; m < 4; ++m) {
        float v = acc[m] + ldT(bias, col0 + cg * 4 + m);
        O[o + m] = v > 0.f ? v : SLOPE * v;
    }
}

__global__ __launch_bounds__(256) void mlp_layer_kernel(
        const float* X, const void* W, size_t woff, const void* bias, size_t boff,
        float* O, const int* flagp) {
    __shared__ float Xs0[64 * 65], Xs1[64 * 65];   // 2 x 16.6 KB
    __shared__ float Ws0[64 * 16], Ws1[64 * 16];   // 2 x 4 KB
    if (*flagp) mlp_layer_body<__hip_bfloat16>(X, (const __hip_bfloat16*)W + woff,
                                               (const __hip_bfloat16*)bias + boff, O,
                                               Xs0, Xs1, Ws0, Ws1);
    else        mlp_layer_body<float>(X, (const float*)W + woff,
                                      (const float*)bias + boff, O, Xs0, Xs1, Ws0, Ws1);
}

// ---------------- final dot: out[b] = X[b,:] . w + ob ----------------
__global__ void final_kernel(const float* __restrict__ X, const void* w, const void* ob,
                             void* out, const int* flagp) {
    int b = blockIdx.x, t = threadIdx.x;
    int bf = *flagp;
    float p = 0.f;
    for (int j = t; j < H2; j += 256)
        p += X[(size_t)b * H2 + j] * loadin(w, j, bf);
    __shared__ float red[256];
    red[t] = p;
    __syncthreads();
    for (int s = 128; s > 0; s >>= 1) {
        if (t < s) red[t] += red[t + s];
        __syncthreads();
    }
    if (t == 0) {
        float v = red[0] + loadin(ob, 0, bf);
        if (bf) ((__hip_bfloat16*)out)[b] = __float2bfloat16(v);
        else    ((float*)out)[b] = v;
    }
}

extern "C" void kernel_launch(void* const* d_in, const int* in_sizes, int n_in,
                              void* d_out, int out_size, void* d_ws, size_t ws_size,
                              hipStream_t stream) {
    const void* x_in = d_in[0];
    const void* c1w = d_in[2];  const void* c1b = d_in[3];
    const void* c2w = d_in[4];  const void* c2b = d_in[5];
    const void* c3w = d_in[6];  const void* c3b = d_in[7];
    const void* gam = d_in[8];  const void* bet = d_in[9];
    const void* lw  = d_in[10]; const void* lb  = d_in[11];
    const void* ow  = d_in[12]; const void* obb = d_in[13];

    char* w = (char*)d_ws;
    int* flagp = (int*)w;                    w += 16;
    float* xf = (float*)w;                   w += (size_t)NN * FIN * 4;
    unsigned char* nbr = (unsigned char*)w;  w += (size_t)NN * KNN;
    float* t5a = (float*)w;                  w += (size_t)NN * FIN * 4;
    float* t5b = (float*)w;                  w += (size_t)NN * FIN * 4;
    float* bufA = (float*)w;                 w += (size_t)NN * HH * 4;
    float* bufB = (float*)w;                 w += (size_t)NN * HH * 4;
    float* bufC = (float*)w;                 w += (size_t)NN * HH * 4;
    float* bufD = (float*)w;                 w += (size_t)NN * HH * 4;
    float* g = (float*)w;                    w += (size_t)BB * H2 * 4;
    float* mA = (float*)w;                   w += (size_t)BB * H2 * 4;
    float* mB = (float*)w;                   w += (size_t)BB * H2 * 4;

    float dinv = 1.0f / sqrtf((float)KNN);
    float nrm = dinv * dinv;

    detect_kernel<<<1, 1, 0, stream>>>(gam, flagp);
    cvt_kernel<<<(NN * FIN + 255) / 256, 256, 0, stream>>>(x_in, flagp, xf, NN * FIN);
    knn_kernel<<<NN, 256, 0, stream>>>(xf, nbr);

    dim3 conv_grid32(NN / 32);
    dim3 agg_grid(BB, 4, 4);

    // ---- conv1 (Cin=5) ----
    agg5x2_kernel<<<BB, 256, 0, stream>>>(xf, nbr, t5a, t5b, nrm);
    tagmm5_kernel<<<NN / 16, 256, 0, stream>>>(xf, t5a, t5b, c1w, c1b, bufA, flagp);
    pool_kernel<<<BB, 1024, 0, stream>>>(bufA, g, 0);

    // ---- conv2: bufA -> bufD ----
    agg128_kernel<<<agg_grid, 256, 0, stream>>>(bufA, nbr, bufB, nrm);
    agg128_kernel<<<agg_grid, 256, 0, stream>>>(bufB, nbr, bufC, nrm);
    tagmm128_kernel<<<conv_grid32, 256, 0, stream>>>(bufA, bufB, bufC, c2w, c2b, bufD, flagp);
    pool_kernel<<<BB, 1024, 0, stream>>>(bufD, g, 256);

    // ---- conv3: bufD -> bufC ----
    agg128_kernel<<<agg_grid, 256, 0, stream>>>(bufD, nbr, bufA, nrm);
    agg128_kernel<<<agg_grid, 256, 0, stream>>>(bufA, nbr, bufB, nrm);
    tagmm128_kernel<<<conv_grid32, 256, 0, stream>>>(bufD, bufA, bufB, c3w, c3b, bufC, flagp);
    pool_kernel<<<BB, 1024, 0, stream>>>(bufC, g, 512);

    // ---- batchnorm ----
    bn_kernel<<<6, 128, 0, stream>>>(g, gam, bet, flagp);

    // ---- MLP: 5 GEMM layers, then final dot ----
    float* src = g;
    for (int i = 0; i < 5; ++i) {
        float* dst = (i % 2 == 0) ? mA : mB;
        mlp_layer_kernel<<<H2 / 16, 256, 0, stream>>>(src, lw, (size_t)i * H2 * H2,
                                                      lb, (size_t)i * H2, dst, flagp);
        src = dst;
    }
    final_kernel<<<BB, 256, 0, stream>>>(src, ow, obb, d_out, flagp);
}